// Round 22
// baseline (38.966 us; speedup 1.0000x reference)
//
#include <hip/hip_runtime.h>

// SoftSmoothAP on MI355X. B=384, C=48, D=512. Output: scalar f32 loss = 1 - AP.
//
//   simk = clamp(sim*100*log2e, +-45); E = 2^simk; sg(p,q) = Eq/(Eq+Ep)
//   denom[i,p] = 0.5 + F_i(kp),  F_i(x) = sum_q sigma(kq - x)
//   F_i at 64 uniform nodes IN-BLOCK, cubic Lagrange at each kp (validated:
//   absmax 0.0 across R19-R21); self-p exact: 1 + 2^-45*SE.
//   loss = 1 - (1/B) sum_{i,c} sl*w[c] * sum_{p in P_c} (0.5 + sum_{q in P_c} sg)/denom
//
// R22: phase B gathers vectorized -- per-class Eq staged into a 4-ALIGNED,
// ZERO-PADDED LDS array (sigE(0,Ep)=0 exactly, so pad slots are free and the
// tail loop disappears). Inner loop: 1 ds_read_b128 + 4 sigE (was 4 b32).
// Everything else = R21.

#define BB 384
#define CC 48
#define DD 512
#define MAXE 3072
#define MAXE4 3264
#define NNODE 64
#define SCALE 144.269504089f  // 100 * log2(e)

__device__ __forceinline__ float sigE(float Eq, float Ep) {
    return Eq * __builtin_amdgcn_rcpf(Eq + Ep);
}

// ---- 1. sim tiles (blocks 0..143 = 36 tiles x 4 k-chunks) + masks (block 144)
__global__ __launch_bounds__(256) void simprep_kernel(
    const float* __restrict__ preds, const float* __restrict__ softlabels,
    float* __restrict__ simpart, float* __restrict__ wclass,
    uint2* __restrict__ maskbuf, float* __restrict__ out) {
    int tid = threadIdx.x;

    if (blockIdx.x < 144) {
        int t = blockIdx.x >> 2, kc = blockIdx.x & 3;
        int bi = t / 6, bj = t % 6;
        __shared__ __align__(16) float s_a[128][68];
        __shared__ __align__(16) float s_b[128][68];
        int kbase = kc * 128;
#pragma unroll
        for (int it = 0; it < 8; ++it) {
            int idx = it * 256 + tid;
            int r = idx >> 5;
            int c4 = idx & 31;
            float4 va = *reinterpret_cast<const float4*>(
                preds + (bi * 64 + r) * DD + kbase + c4 * 4);
            float4 vb = *reinterpret_cast<const float4*>(
                preds + (bj * 64 + r) * DD + kbase + c4 * 4);
            s_a[c4 * 4 + 0][r] = va.x; s_a[c4 * 4 + 1][r] = va.y;
            s_a[c4 * 4 + 2][r] = va.z; s_a[c4 * 4 + 3][r] = va.w;
            s_b[c4 * 4 + 0][r] = vb.x; s_b[c4 * 4 + 1][r] = vb.y;
            s_b[c4 * 4 + 2][r] = vb.z; s_b[c4 * 4 + 3][r] = vb.w;
        }
        __syncthreads();
        int ty = tid >> 4, tx = tid & 15;
        float4 acc0 = {0,0,0,0}, acc1 = {0,0,0,0}, acc2 = {0,0,0,0}, acc3 = {0,0,0,0};
#pragma unroll 4
        for (int k = 0; k < 128; ++k) {
            float4 a4 = *reinterpret_cast<const float4*>(&s_a[k][ty * 4]);
            float4 b4 = *reinterpret_cast<const float4*>(&s_b[k][tx * 4]);
            acc0.x += a4.x * b4.x; acc0.y += a4.x * b4.y; acc0.z += a4.x * b4.z; acc0.w += a4.x * b4.w;
            acc1.x += a4.y * b4.x; acc1.y += a4.y * b4.y; acc1.z += a4.y * b4.z; acc1.w += a4.y * b4.w;
            acc2.x += a4.z * b4.x; acc2.y += a4.z * b4.y; acc2.z += a4.z * b4.z; acc2.w += a4.z * b4.w;
            acc3.x += a4.w * b4.x; acc3.y += a4.w * b4.y; acc3.z += a4.w * b4.z; acc3.w += a4.w * b4.w;
        }
        if (blockIdx.x == 0 && tid == 0) out[0] = 1.0f;
        float* dst = simpart + kc * (BB * BB) + (bi * 64 + ty * 4) * BB + bj * 64 + tx * 4;
        *reinterpret_cast<float4*>(dst + 0 * BB) = acc0;
        *reinterpret_cast<float4*>(dst + 1 * BB) = acc1;
        *reinterpret_cast<float4*>(dst + 2 * BB) = acc2;
        *reinterpret_cast<float4*>(dst + 3 * BB) = acc3;
    } else {
        // ---- masks + class weights only ----
        __shared__ unsigned int s_mlo[BB];
        __shared__ unsigned int s_mhi[BB];
        int wave = tid >> 6, lane = tid & 63;

        for (int p = tid; p < BB; p += 256) {
            const float4* rowp = reinterpret_cast<const float4*>(softlabels + p * CC);
            unsigned int lo = 0, hi = 0;
#pragma unroll
            for (int v = 0; v < 12; ++v) {
                float4 x = rowp[v];
                unsigned int b = (x.x > 0.f ? 1u : 0u) | (x.y > 0.f ? 2u : 0u) |
                                 (x.z > 0.f ? 4u : 0u) | (x.w > 0.f ? 8u : 0u);
                if (v < 8) lo |= b << (4 * v);
                else       hi |= b << (4 * (v - 8));
            }
            s_mlo[p] = lo;
            s_mhi[p] = hi;
            maskbuf[p] = make_uint2(lo, hi);
        }
        __syncthreads();
        for (int c = wave; c < CC; c += 4) {
            int cnt = 0;
#pragma unroll
            for (int t = 0; t < BB / 64; ++t) {
                int p = t * 64 + lane;
                bool pos = ((c < 32 ? (s_mlo[p] >> c) : (s_mhi[p] >> (c - 32))) & 1u) != 0u;
                cnt += __popcll(__ballot(pos));
            }
            if (lane == 0) wclass[c] = (cnt >= 4) ? (1.0f / (float)cnt) : 0.0f;
        }
    }
}

// ---- 2. megaF: row/block; self-prep + 64-node spline + vectorized phase B ----
__global__ __launch_bounds__(1024) void mega_kernel(
    const float* __restrict__ simpart, const float* __restrict__ softlabels,
    const float* __restrict__ wclass, const uint2* __restrict__ maskbuf,
    float* __restrict__ out) {
    int i = blockIdx.x;
    int tid = threadIdx.x;
    int wave = tid >> 6, lane = tid & 63;

    __shared__ float s_sk[BB];
    __shared__ __align__(16) float s_E[BB];
    __shared__ uint2 s_mq[BB];
    __shared__ int s_cnt[CC];
    __shared__ int s_soff[CC + 1];
    __shared__ int s_aoff[CC + 1];
    __shared__ float s_wsl[CC];
    __shared__ int s_fp[MAXE];
    __shared__ __align__(16) float s_EqA[MAXE4];
    __shared__ float s_Fp[16][NNODE];
    __shared__ float s_F[NNODE];
    __shared__ float s_inv[BB];
    __shared__ float s_red[16];
    __shared__ float s_mx[16], s_mn[16], s_se[16];

    // phase 0: sim row -> sk, E; masks; wsl; zero padded Eq array
    if (tid < BB) {
        int x = i * BB + tid;
        float sim = (simpart[x] + simpart[BB * BB + x]) +
                    (simpart[2 * BB * BB + x] + simpart[3 * BB * BB + x]);
        float sk = fminf(fmaxf(sim * SCALE, -45.0f), 45.0f);  // only self-sim clamps
        s_sk[tid] = sk;
        s_E[tid] = __builtin_amdgcn_exp2f(sk);
        s_mq[tid] = maskbuf[tid];
    }
    if (tid < CC) s_wsl[tid] = wclass[tid] * softlabels[i * CC + tid];
    for (int e = tid; e < MAXE4; e += 1024) s_EqA[e] = 0.f;
    __syncthreads();

    // self-prep: counts -> dual scan (entries + 4-aligned) -> pack fp + EqA
    for (int c = wave; c < CC; c += 16) {
        int cnt = 0;
#pragma unroll
        for (int t = 0; t < BB / 64; ++t) {
            int p = t * 64 + lane;
            unsigned int mb = (c < 32) ? s_mq[p].x : s_mq[p].y;
            cnt += __popcll(__ballot(((mb >> (c & 31)) & 1u) != 0u));
        }
        if (lane == 0) s_cnt[c] = cnt;
    }
    __syncthreads();
    if (tid < 64) {
        int v = (tid < CC) ? s_cnt[tid] : 0;
        int v4 = (v + 3) & ~3;
#pragma unroll
        for (int d = 1; d < 64; d <<= 1) {
            int o = __shfl_up(v, d, 64);
            int o4 = __shfl_up(v4, d, 64);
            if (tid >= d) { v += o; v4 += o4; }
        }
        if (tid < CC) { s_soff[tid + 1] = v; s_aoff[tid + 1] = v4; }
        if (tid == 0) { s_soff[0] = 0; s_aoff[0] = 0; }
    }
    __syncthreads();
    int nE = s_soff[CC];
    for (int c = wave; c < CC; c += 16) {
        int base = s_soff[c];
        int abase = s_aoff[c];
        int rel = 0;
#pragma unroll
        for (int t = 0; t < BB / 64; ++t) {
            int p = t * 64 + lane;
            unsigned int mb = (c < 32) ? s_mq[p].x : s_mq[p].y;
            bool pos = ((mb >> (c & 31)) & 1u) != 0u;
            unsigned long long m = __ballot(pos);
            if (pos) {
                int idx = __popcll(m & ((1ull << lane) - 1ull));
                s_fp[base + rel + idx] = (c << 16) | p;
                s_EqA[abase + rel + idx] = s_E[p];
            }
            rel += __popcll(m);
        }
    }

    // min (all) / max (excl. self) / SE (excl. self)
    float mx = -1e30f, mn = 1e30f, se = 0.f;
    if (tid < BB) {
        float v = s_sk[tid];
        mn = v;
        if (tid != i) { mx = v; se = s_E[tid]; }
    }
#pragma unroll
    for (int off = 32; off > 0; off >>= 1) {
        mx = fmaxf(mx, __shfl_xor(mx, off, 64));
        mn = fminf(mn, __shfl_xor(mn, off, 64));
        se += __shfl_xor(se, off, 64);
    }
    if (lane == 0) { s_mx[wave] = mx; s_mn[wave] = mn; s_se[wave] = se; }
    __syncthreads();
    mx = s_mx[0]; mn = s_mn[0]; se = s_se[0];
#pragma unroll
    for (int w = 1; w < 16; ++w) {
        mx = fmaxf(mx, s_mx[w]);
        mn = fminf(mn, s_mn[w]);
        se += s_se[w];
    }
    float lo = mn - 0.5f;
    float rng = fmaxf((mx + 0.5f) - lo, 1e-3f);
    float step = rng * (1.0f / (NNODE - 1));
    float invh = (NNODE - 1) / rng;

    // F at 64 nodes: lane = node, wave = q-chunk of 24
    {
        float En = __builtin_amdgcn_exp2f(lo + (float)lane * step);
        const float4* sv = reinterpret_cast<const float4*>(s_E + wave * 24);
        float a0 = 0.f, a1 = 0.f, a2 = 0.f;
#pragma unroll
        for (int t = 0; t < 6; t += 3) {
            float4 v0 = sv[t], v1 = sv[t + 1], v2 = sv[t + 2];
            a0 += sigE(v0.x, En) + sigE(v0.w, En);
            a1 += sigE(v0.y, En) + sigE(v1.x, En);
            a2 += sigE(v0.z, En) + sigE(v1.y, En);
            a0 += sigE(v1.z, En) + sigE(v2.y, En);
            a1 += sigE(v1.w, En) + sigE(v2.z, En);
            a2 += sigE(v2.x, En) + sigE(v2.w, En);
        }
        s_Fp[wave][lane] = (a0 + a1) + a2;
    }
    __syncthreads();
    if (tid < NNODE) {
        float f = 0.f;
#pragma unroll
        for (int c16 = 0; c16 < 16; ++c16) f += s_Fp[c16][tid];
        s_F[tid] = f;
    }
    __syncthreads();

    // denominators: cubic Lagrange; self-p exact tail
    if (tid < BB) {
        float d;
        if (tid == i) {
            d = 1.0f + se * 2.84217094e-14f;  // 2^-45 * SE
        } else {
            float t = (s_sk[tid] - lo) * invh;
            int j = (int)floorf(t);
            j = min(max(j, 1), NNODE - 3);
            float u = t - (float)j;
            float f0 = s_F[j - 1], f1 = s_F[j], f2 = s_F[j + 1], f3 = s_F[j + 2];
            float um1 = u + 1.f, u1 = u - 1.f, u2 = u - 2.f;
            float c0 = -u * u1 * u2 * (1.f / 6.f);
            float c1 = um1 * u1 * u2 * (1.f / 2.f);
            float c2 = -um1 * u * u2 * (1.f / 2.f);
            float c3 = um1 * u * u1 * (1.f / 6.f);
            d = 0.5f + (c0 * f0 + c1 * f1) + (c2 * f2 + c3 * f3);
        }
        s_inv[tid] = __builtin_amdgcn_rcpf(d);
    }
    __syncthreads();

    // phase B: exact; float4 gathers over 4-aligned zero-padded Eq lists
    float part = 0.f;
    for (int e = tid; e < nE; e += 1024) {
        int pk = s_fp[e];
        int c = pk >> 16, p = pk & 0xFFFF;
        int aoff = s_aoff[c];
        int m4 = s_aoff[c + 1] - aoff;  // multiple of 4; pad slots are Eq=0 -> sigE=0
        float Ep = s_E[p];
        const float4* eq4 = reinterpret_cast<const float4*>(s_EqA + aoff);
        float b0 = 0.f, b1 = 0.f, b2 = 0.f, b3 = 0.f;
        for (int j = 0; j < (m4 >> 2); ++j) {
            float4 v = eq4[j];
            b0 += sigE(v.x, Ep);
            b1 += sigE(v.y, Ep);
            b2 += sigE(v.z, Ep);
            b3 += sigE(v.w, Ep);
        }
        float s = (b0 + b1) + (b2 + b3);
        // s includes q==p (=0.5): numerator = 0.5 + s
        part += (0.5f + s) * s_inv[p] * s_wsl[c];
    }

    for (int off = 32; off > 0; off >>= 1) part += __shfl_down(part, off, 64);
    if (lane == 0) s_red[wave] = part;
    __syncthreads();
    if (tid == 0) {
        float tot = 0.f;
#pragma unroll
        for (int w = 0; w < 16; ++w) tot += s_red[w];
        atomicAdd(out, -tot * (1.0f / (float)BB));
    }
}

extern "C" void kernel_launch(void* const* d_in, const int* in_sizes, int n_in,
                              void* d_out, int out_size, void* d_ws, size_t ws_size,
                              hipStream_t stream) {
    const float* preds = (const float*)d_in[0];       // (384,512) f32
    const float* softlabels = (const float*)d_in[1];  // (384,48) f32
    float* out = (float*)d_out;

    char* ws = (char*)d_ws;
    float* simpart = (float*)(ws + 0);        // 2359296
    float* wclass  = (float*)(ws + 2359296);  // 192
    uint2* maskbuf = (uint2*)(ws + 2359488);  // 3072

    simprep_kernel<<<145, 256, 0, stream>>>(preds, softlabels, simpart, wclass,
                                            maskbuf, out);
    mega_kernel<<<BB, 1024, 0, stream>>>(simpart, softlabels, wclass, maskbuf, out);
}

// Round 23
// 32.855 us; speedup vs baseline: 1.1860x; 1.1860x over previous
//
#include <hip/hip_runtime.h>

// SoftSmoothAP on MI355X. B=384, C=48, D=512. Output: scalar f32 loss = 1 - AP.
//
//   simk = clamp(sim*100*log2e, +-45); E = 2^simk; sg(p,q) = Eq/(Eq+Ep)
//   denom[i,p] = 0.5 + F_i(kp),  F_i(x) = sum_q sigma(kq - x)
//   F_i at 64 uniform nodes IN-BLOCK (F is ultra-smooth: sum of 384 smeared
//   sigmoids -> cubic interp effectively exact; R19-R21 absmax 0.0), cubic
//   Lagrange at each kp; self-p exact: 1 + 2^-45*SE.
//   loss = 1 - (1/B) sum_{i,c} sl*w[c] * sum_{p in P_c} (0.5 + sum_{q in P_c} sg)/denom
//
// R23 = R21 EXACT REVERT (best measured: 32.8us). R22's vectorized phase B
// regressed (+6.2us): zero-init prologue + dual scan + scattered pack writes +
// un-unrolled runtime-trip loop cost more than the b128 reads saved. Final
// budget: ~15us fixed overhead + ~5us simprep + ~11us mega (mega within ~20%
// of its 36M-sigE trans-issue floor; residual = 384-on-256-CU tail).

#define BB 384
#define CC 48
#define DD 512
#define MAXE 3072
#define NNODE 64
#define SCALE 144.269504089f  // 100 * log2(e)

__device__ __forceinline__ float sigE(float Eq, float Ep) {
    return Eq * __builtin_amdgcn_rcpf(Eq + Ep);
}

// ---- 1. sim tiles (blocks 0..143 = 36 tiles x 4 k-chunks) + masks (block 144)
__global__ __launch_bounds__(256) void simprep_kernel(
    const float* __restrict__ preds, const float* __restrict__ softlabels,
    float* __restrict__ simpart, float* __restrict__ wclass,
    uint2* __restrict__ maskbuf, float* __restrict__ out) {
    int tid = threadIdx.x;

    if (blockIdx.x < 144) {
        int t = blockIdx.x >> 2, kc = blockIdx.x & 3;
        int bi = t / 6, bj = t % 6;
        __shared__ __align__(16) float s_a[128][68];
        __shared__ __align__(16) float s_b[128][68];
        int kbase = kc * 128;
#pragma unroll
        for (int it = 0; it < 8; ++it) {
            int idx = it * 256 + tid;
            int r = idx >> 5;
            int c4 = idx & 31;
            float4 va = *reinterpret_cast<const float4*>(
                preds + (bi * 64 + r) * DD + kbase + c4 * 4);
            float4 vb = *reinterpret_cast<const float4*>(
                preds + (bj * 64 + r) * DD + kbase + c4 * 4);
            s_a[c4 * 4 + 0][r] = va.x; s_a[c4 * 4 + 1][r] = va.y;
            s_a[c4 * 4 + 2][r] = va.z; s_a[c4 * 4 + 3][r] = va.w;
            s_b[c4 * 4 + 0][r] = vb.x; s_b[c4 * 4 + 1][r] = vb.y;
            s_b[c4 * 4 + 2][r] = vb.z; s_b[c4 * 4 + 3][r] = vb.w;
        }
        __syncthreads();
        int ty = tid >> 4, tx = tid & 15;
        float4 acc0 = {0,0,0,0}, acc1 = {0,0,0,0}, acc2 = {0,0,0,0}, acc3 = {0,0,0,0};
#pragma unroll 4
        for (int k = 0; k < 128; ++k) {
            float4 a4 = *reinterpret_cast<const float4*>(&s_a[k][ty * 4]);
            float4 b4 = *reinterpret_cast<const float4*>(&s_b[k][tx * 4]);
            acc0.x += a4.x * b4.x; acc0.y += a4.x * b4.y; acc0.z += a4.x * b4.z; acc0.w += a4.x * b4.w;
            acc1.x += a4.y * b4.x; acc1.y += a4.y * b4.y; acc1.z += a4.y * b4.z; acc1.w += a4.y * b4.w;
            acc2.x += a4.z * b4.x; acc2.y += a4.z * b4.y; acc2.z += a4.z * b4.z; acc2.w += a4.z * b4.w;
            acc3.x += a4.w * b4.x; acc3.y += a4.w * b4.y; acc3.z += a4.w * b4.z; acc3.w += a4.w * b4.w;
        }
        if (blockIdx.x == 0 && tid == 0) out[0] = 1.0f;
        float* dst = simpart + kc * (BB * BB) + (bi * 64 + ty * 4) * BB + bj * 64 + tx * 4;
        *reinterpret_cast<float4*>(dst + 0 * BB) = acc0;
        *reinterpret_cast<float4*>(dst + 1 * BB) = acc1;
        *reinterpret_cast<float4*>(dst + 2 * BB) = acc2;
        *reinterpret_cast<float4*>(dst + 3 * BB) = acc3;
    } else {
        // ---- masks + class weights only (scan/pack done in mega) ----
        __shared__ unsigned int s_mlo[BB];
        __shared__ unsigned int s_mhi[BB];
        int wave = tid >> 6, lane = tid & 63;

        for (int p = tid; p < BB; p += 256) {
            const float4* rowp = reinterpret_cast<const float4*>(softlabels + p * CC);
            unsigned int lo = 0, hi = 0;
#pragma unroll
            for (int v = 0; v < 12; ++v) {
                float4 x = rowp[v];
                unsigned int b = (x.x > 0.f ? 1u : 0u) | (x.y > 0.f ? 2u : 0u) |
                                 (x.z > 0.f ? 4u : 0u) | (x.w > 0.f ? 8u : 0u);
                if (v < 8) lo |= b << (4 * v);
                else       hi |= b << (4 * (v - 8));
            }
            s_mlo[p] = lo;
            s_mhi[p] = hi;
            maskbuf[p] = make_uint2(lo, hi);
        }
        __syncthreads();
        for (int c = wave; c < CC; c += 4) {
            int cnt = 0;
#pragma unroll
            for (int t = 0; t < BB / 64; ++t) {
                int p = t * 64 + lane;
                bool pos = ((c < 32 ? (s_mlo[p] >> c) : (s_mhi[p] >> (c - 32))) & 1u) != 0u;
                cnt += __popcll(__ballot(pos));
            }
            if (lane == 0) wclass[c] = (cnt >= 4) ? (1.0f / (float)cnt) : 0.0f;
        }
    }
}

// ---- 2. megaF: row/block; self-prep + in-block 64-node spline + exact phase B
__global__ __launch_bounds__(1024) void mega_kernel(
    const float* __restrict__ simpart, const float* __restrict__ softlabels,
    const float* __restrict__ wclass, const uint2* __restrict__ maskbuf,
    float* __restrict__ out) {
    int i = blockIdx.x;
    int tid = threadIdx.x;
    int wave = tid >> 6, lane = tid & 63;

    __shared__ float s_sk[BB];
    __shared__ __align__(16) float s_E[BB];
    __shared__ uint2 s_mq[BB];
    __shared__ int s_cnt[CC];
    __shared__ int s_soff[CC + 1];
    __shared__ float s_wsl[CC];
    __shared__ int s_fp[MAXE];
    __shared__ float s_Eq[MAXE];
    __shared__ float s_Fp[16][NNODE];
    __shared__ float s_F[NNODE];
    __shared__ float s_inv[BB];
    __shared__ float s_red[16];
    __shared__ float s_mx[16], s_mn[16], s_se[16];

    // phase 0: sim row -> sk, E; masks; wsl
    if (tid < BB) {
        int x = i * BB + tid;
        float sim = (simpart[x] + simpart[BB * BB + x]) +
                    (simpart[2 * BB * BB + x] + simpart[3 * BB * BB + x]);
        float sk = fminf(fmaxf(sim * SCALE, -45.0f), 45.0f);  // only self-sim clamps
        s_sk[tid] = sk;
        s_E[tid] = __builtin_amdgcn_exp2f(sk);
        s_mq[tid] = maskbuf[tid];
    }
    if (tid < CC) s_wsl[tid] = wclass[tid] * softlabels[i * CC + tid];
    __syncthreads();

    // self-prep: counts -> scan -> flat pack, all in LDS
    for (int c = wave; c < CC; c += 16) {
        int cnt = 0;
#pragma unroll
        for (int t = 0; t < BB / 64; ++t) {
            int p = t * 64 + lane;
            unsigned int mb = (c < 32) ? s_mq[p].x : s_mq[p].y;
            cnt += __popcll(__ballot(((mb >> (c & 31)) & 1u) != 0u));
        }
        if (lane == 0) s_cnt[c] = cnt;
    }
    __syncthreads();
    if (tid < 64) {
        int v = (tid < CC) ? s_cnt[tid] : 0;
#pragma unroll
        for (int d = 1; d < 64; d <<= 1) {
            int o = __shfl_up(v, d, 64);
            if (tid >= d) v += o;
        }
        if (tid < CC) s_soff[tid + 1] = v;
        if (tid == 0) s_soff[0] = 0;
    }
    __syncthreads();
    int nE = s_soff[CC];
    for (int c = wave; c < CC; c += 16) {
        int base = s_soff[c];
#pragma unroll
        for (int t = 0; t < BB / 64; ++t) {
            int p = t * 64 + lane;
            unsigned int mb = (c < 32) ? s_mq[p].x : s_mq[p].y;
            bool pos = ((mb >> (c & 31)) & 1u) != 0u;
            unsigned long long m = __ballot(pos);
            if (pos) s_fp[base + __popcll(m & ((1ull << lane) - 1ull))] = (c << 16) | p;
            base += __popcll(m);
        }
    }
    __syncthreads();

    // Eq staging + min/max/SE reductions
    for (int e = tid; e < nE; e += 1024) s_Eq[e] = s_E[s_fp[e] & 0xFFFF];
    float mx = -1e30f, mn = 1e30f, se = 0.f;
    if (tid < BB) {
        float v = s_sk[tid];
        mn = v;
        if (tid != i) { mx = v; se = s_E[tid]; }
    }
#pragma unroll
    for (int off = 32; off > 0; off >>= 1) {
        mx = fmaxf(mx, __shfl_xor(mx, off, 64));
        mn = fminf(mn, __shfl_xor(mn, off, 64));
        se += __shfl_xor(se, off, 64);
    }
    if (lane == 0) { s_mx[wave] = mx; s_mn[wave] = mn; s_se[wave] = se; }
    __syncthreads();
    mx = s_mx[0]; mn = s_mn[0]; se = s_se[0];
#pragma unroll
    for (int w = 1; w < 16; ++w) {
        mx = fmaxf(mx, s_mx[w]);
        mn = fminf(mn, s_mn[w]);
        se += s_se[w];
    }
    float lo = mn - 0.5f;
    float rng = fmaxf((mx + 0.5f) - lo, 1e-3f);
    float step = rng * (1.0f / (NNODE - 1));
    float invh = (NNODE - 1) / rng;

    // F at 64 nodes: lane = node, wave = q-chunk of 24; broadcast LDS reads
    {
        float En = __builtin_amdgcn_exp2f(lo + (float)lane * step);
        const float4* sv = reinterpret_cast<const float4*>(s_E + wave * 24);
        float a0 = 0.f, a1 = 0.f, a2 = 0.f;
#pragma unroll
        for (int t = 0; t < 6; t += 3) {
            float4 v0 = sv[t], v1 = sv[t + 1], v2 = sv[t + 2];
            a0 += sigE(v0.x, En) + sigE(v0.w, En);
            a1 += sigE(v0.y, En) + sigE(v1.x, En);
            a2 += sigE(v0.z, En) + sigE(v1.y, En);
            a0 += sigE(v1.z, En) + sigE(v2.y, En);
            a1 += sigE(v1.w, En) + sigE(v2.z, En);
            a2 += sigE(v2.x, En) + sigE(v2.w, En);
        }
        s_Fp[wave][lane] = (a0 + a1) + a2;
    }
    __syncthreads();
    if (tid < NNODE) {
        float f = 0.f;
#pragma unroll
        for (int c16 = 0; c16 < 16; ++c16) f += s_Fp[c16][tid];
        s_F[tid] = f;
    }
    __syncthreads();

    // denominators: cubic Lagrange; self-p exact tail
    if (tid < BB) {
        float d;
        if (tid == i) {
            d = 1.0f + se * 2.84217094e-14f;  // 2^-45 * SE
        } else {
            float t = (s_sk[tid] - lo) * invh;
            int j = (int)floorf(t);
            j = min(max(j, 1), NNODE - 3);
            float u = t - (float)j;
            float f0 = s_F[j - 1], f1 = s_F[j], f2 = s_F[j + 1], f3 = s_F[j + 2];
            float um1 = u + 1.f, u1 = u - 1.f, u2 = u - 2.f;
            float c0 = -u * u1 * u2 * (1.f / 6.f);
            float c1 = um1 * u1 * u2 * (1.f / 2.f);
            float c2 = -um1 * u * u2 * (1.f / 2.f);
            float c3 = um1 * u * u1 * (1.f / 6.f);
            d = 0.5f + (c0 * f0 + c1 * f1) + (c2 * f2 + c3 * f3);
        }
        s_inv[tid] = __builtin_amdgcn_rcpf(d);
    }
    __syncthreads();

    // phase B: exact, entry-parallel over full list
    float part = 0.f;
    for (int e = tid; e < nE; e += 1024) {
        int pk = s_fp[e];
        int c = pk >> 16, p = pk & 0xFFFF;
        int off = s_soff[c], m = s_soff[c + 1] - off;
        float Ep = s_E[p];
        float b0 = 0.f, b1 = 0.f, b2 = 0.f, b3 = 0.f;
        int j = 0;
        for (; j + 3 < m; j += 4) {
            b0 += sigE(s_Eq[off + j], Ep);
            b1 += sigE(s_Eq[off + j + 1], Ep);
            b2 += sigE(s_Eq[off + j + 2], Ep);
            b3 += sigE(s_Eq[off + j + 3], Ep);
        }
        for (; j < m; ++j) b0 += sigE(s_Eq[off + j], Ep);
        float s = (b0 + b1) + (b2 + b3);
        // s includes q==p (=0.5): numerator = 0.5 + s
        part += (0.5f + s) * s_inv[p] * s_wsl[c];
    }

    for (int off = 32; off > 0; off >>= 1) part += __shfl_down(part, off, 64);
    if (lane == 0) s_red[wave] = part;
    __syncthreads();
    if (tid == 0) {
        float tot = 0.f;
#pragma unroll
        for (int w = 0; w < 16; ++w) tot += s_red[w];
        atomicAdd(out, -tot * (1.0f / (float)BB));
    }
}

extern "C" void kernel_launch(void* const* d_in, const int* in_sizes, int n_in,
                              void* d_out, int out_size, void* d_ws, size_t ws_size,
                              hipStream_t stream) {
    const float* preds = (const float*)d_in[0];       // (384,512) f32
    const float* softlabels = (const float*)d_in[1];  // (384,48) f32
    float* out = (float*)d_out;

    char* ws = (char*)d_ws;
    float* simpart = (float*)(ws + 0);        // 2359296
    float* wclass  = (float*)(ws + 2359296);  // 192
    uint2* maskbuf = (uint2*)(ws + 2359488);  // 3072

    simprep_kernel<<<145, 256, 0, stream>>>(preds, softlabels, simpart, wclass,
                                            maskbuf, out);
    mega_kernel<<<BB, 1024, 0, stream>>>(simpart, softlabels, wclass, maskbuf, out);
}